// Round 1
// baseline (74.369 us; speedup 1.0000x reference)
//
#include <hip/hip_runtime.h>
#include <math.h>

// Problem constants (match reference)
#define Hh 121
#define Ww 121
#define NPI 200          // N_INTERP
#define Bb 8
#define Ee 225
#define EPAD 256         // padded electrode count in workspace
#define NPIX (Hh * Ww)   // 14641
#define TS 8             // pixel tile side (one wave = 8x8 tile)
#define MAXC 232         // 225 survivors + pad

#define XLOWc   (-4200.0f)
#define RSTEP   (199.0f / 8400.0f)       // 1/STEP
#define ODXc     4340.0f
#define PIc      3.14159265358979323846f
#define INV2PI   0.15915494309189535f    // v_sin/v_cos take revolutions
#define INV4PI   0.07957747154594767f
#define NHL     (-0.72134752044448170368f)  // -0.5 * log2(e)
#define CULL_T   20.0f   // drop terms provably < bright * 2^-20
#define NL2_045  1.15200309344504995f    // -log2(0.45)

#if __has_builtin(__builtin_amdgcn_exp2f)
#define EXP2F(x) __builtin_amdgcn_exp2f(x)
#else
#define EXP2F(x) exp2f(x)
#endif
#if __has_builtin(__builtin_amdgcn_logf)
#define LOG2F(x) __builtin_amdgcn_logf(x)
#else
#define LOG2F(x) log2f(x)
#endif
#if __has_builtin(__builtin_amdgcn_sinf)
#define SINR(x) __builtin_amdgcn_sinf((x) * INV2PI)   // sin(x), x radians
#define COSR(x) __builtin_amdgcn_cosf((x) * INV2PI)
#else
#define SINR(x) sinf(x)
#define COSR(x) cosf(x)
#endif
#if __has_builtin(__builtin_amdgcn_rcpf)
#define RCPF(x) __builtin_amdgcn_rcpf(x)
#else
#define RCPF(x) (1.0f / (x))
#endif

// Round 6 theory: render math floor is ~3-5us; the slack is (a) 64x-redundant
// per-block record recompute with cold scattered slope gathers (poison fill
// evicts L2+L3 every iteration), (b) 16x16 cull AABB vs 16x4 wave extent,
// (c) 2-blocks/CU max-sum imbalance.
//  K1: compute the 8x225 records ONCE -> workspace (32 tiny blocks).
//  K2: 2048 single-wave blocks, 8x8 tiles. Coalesced upfront load of all
//      records, in-wave ballot compaction (no atomics, no cross-wave sync),
//      wave-exact cull AABB, unchanged unroll-4 branch-free render loop.

extern "C" __global__ void __launch_bounds__(64)
mvg_precomp(const float* __restrict__ stim, const float* __restrict__ params,
            const float* __restrict__ elec_x, const float* __restrict__ elec_y,
            const float* __restrict__ slopes,
            float4* __restrict__ cullRec, float4* __restrict__ mARec,
            float2* __restrict__ mBRec)
{
    const int b = blockIdx.x;
    const int e = blockIdx.y * 64 + threadIdx.x;   // 0..255

    float cx = 0.f, cy = 0.f, A = 0.f, Bq = 0.f, C = 0.f, bright = 0.f, R = -1e9f;

    if (e < Ee) {
        const float* p = params + b * 13;
        const float rho = p[0], lam = p[1], osc = p[2];
        const float pa0 = p[3], pa1 = p[4], pa2 = p[5], pa3 = p[6], pa4 = p[7];
        const float impx = p[8], impy = p[9], rot = p[10], locx = p[11];

        const float cr = COSR(rot), sr = SINR(rot);
        const float exl = elec_x[e], eyl = elec_y[e];
        const float exv = exl * cr - eyl * sr + impx;
        const float eyv = exl * sr + eyl * cr + impy;

        // bilinear interp of slopes
        const float offx = locx - ODXc;
        const float qx = (exv - offx - XLOWc) * RSTEP;
        const float qy = (eyv - XLOWc) * RSTEP;
        const float fx = fminf(fmaxf(floorf(qx), 0.0f), (float)(NPI - 2));
        const float fy = fminf(fmaxf(floorf(qy), 0.0f), (float)(NPI - 2));
        const int ix = (int)fx, iy = (int)fy;
        const float ax = fminf(fmaxf(qx - fx, 0.0f), 1.0f);
        const float ay = fminf(fmaxf(qy - fy, 0.0f), 1.0f);
        const float g00 = slopes[iy * NPI + ix];
        const float g01 = slopes[iy * NPI + ix + 1];
        const float g10 = slopes[(iy + 1) * NPI + ix];
        const float g11 = slopes[(iy + 1) * NPI + ix + 1];
        const float top = g00 + ax * (g01 - g00);
        const float bot = g10 + ax * (g11 - g10);
        float th = top + ay * (bot - top);
        th = (th < -0.5f * PIc) ? th + PIc : th;
        th *= osc;

        const float* st = stim + (b * Ee + e) * 3;
        const float freq = st[0], amp = st[1], pdur = st[2];

        const float rho_s = fmaxf(rho * amp * pa3, 1.0f);
        float lam_s = lam * EXP2F(pa4 * (LOG2F(pdur) + NL2_045));
        lam_s = fminf(fmaxf(lam_s, 0.0f), 0.99f);
        bright = (amp > 0.25f)
                   ? (pa0 * EXP2F(pa1 * LOG2F(fmaxf(amp, 1e-5f))) + pa2 * freq)
                   : 0.0f;

        const float temp2 = sqrtf(1.0f - lam_s * lam_s);
        const float sy_ = rho_s * INV4PI * RCPF(temp2);
        const float sx_ = rho_s * temp2 * INV4PI;
        const float s = SINR(th), c = COSR(th);
        const float cov00 = sx_ * c * c + sy_ * s * s;
        const float cov01 = (sx_ - sy_) * s * c;
        const float cov11 = sx_ * s * s + sy_ * c * c;
        const float det  = cov00 * cov11 - cov01 * cov01;
        const float rdet = RCPF(det);
        const float i00 =  cov11 * rdet;
        const float i01 = -cov01 * rdet;
        const float i11 =  cov00 * rdet;

        cx = exv * (1.0f / 70.0f) + 60.0f;   // (x/280+15)*4
        cy = 61.0f - eyv * (1.0f / 70.0f);   // 121 - (y/280+15)*4

        A  = i00 * NHL;
        Bq = i01 * 2.0f * NHL;
        C  = i11 * NHL;

        const float a = -A, bq = -Bq, cc = -C;
        const float lam_min = 0.5f * ((a + cc) - sqrtf((a - cc) * (a - cc) + bq * bq));
        if (bright != 0.0f && lam_min > 0.0f)      R = sqrtf(CULL_T / lam_min) + 0.5f;
        else if (bright != 0.0f)                   R = 1e9f;
    }

    const int idx = b * EPAD + e;
    cullRec[idx] = make_float4(cx, cy, R, 0.f);     // R=-1e9 => never live
    mARec[idx]   = make_float4(cx, cy, A, Bq);
    mBRec[idx]   = make_float2(C, bright);
}

extern "C" __global__ void __launch_bounds__(64)
mvg_render(const float4* __restrict__ cullRec, const float4* __restrict__ mARec,
           const float2* __restrict__ mBRec, float* __restrict__ out)
{
    __shared__ __align__(16) float4 scA[MAXC];  // {cx, cy, A, B}
    __shared__ __align__(8)  float2 scB[MAXC];  // {C, bright}

    const int b    = blockIdx.z;
    const int lane = threadIdx.x;               // 0..63, single wave

    // Wave-exact pixel AABB (8x8 tile)
    const int   jmin = blockIdx.x * TS;
    const int   imin = blockIdx.y * TS;
    const int   jmax = min(jmin + TS - 1, Ww - 1);
    const int   imax = min(imin + TS - 1, Hh - 1);
    const float pxminf = (float)jmin, pxmaxf = (float)jmax;
    const float pyminf = (float)(Hh - 1 - imax), pymaxf = (float)(Hh - 1 - imin);

    // Upfront coalesced load of all 256 record slots (pads have R=-1e9)
    const int base = b * EPAD + lane;
    const float4 c0 = cullRec[base      ], c1 = cullRec[base +  64],
                 c2 = cullRec[base + 128], c3 = cullRec[base + 192];
    const float4 a0 = mARec[base      ], a1 = mARec[base +  64],
                 a2 = mARec[base + 128], a3 = mARec[base + 192];
    const float2 b0 = mBRec[base      ], b1 = mBRec[base +  64],
                 b2 = mBRec[base + 128], b3 = mBRec[base + 192];

    // In-wave ballot compaction: no atomics, no cross-wave sync
    int cnt = 0;
#define CHUNK(cv, av, bv) {                                                    \
        const bool live = (cv.x + cv.z >= pxminf) && (cv.x - cv.z <= pxmaxf) && \
                          (cv.y + cv.z >= pyminf) && (cv.y - cv.z <= pymaxf);   \
        const unsigned long long m = __ballot(live);                            \
        if (live) {                                                             \
            const int pos = cnt + (int)__popcll(m & ((1ull << lane) - 1ull));   \
            scA[pos] = av; scB[pos] = bv;                                       \
        }                                                                       \
        cnt += (int)__popcll(m);                                                \
    }
    CHUNK(c0, a0, b0)
    CHUNK(c1, a1, b1)
    CHUNK(c2, a2, b2)
    CHUNK(c3, a3, b3)
#undef CHUNK

    // zero-pad to multiple of 4 (zero rec contributes bright*exp2(0)=0)
    if (lane < 4) {
        scA[cnt + lane] = make_float4(0.f, 0.f, 0.f, 0.f);
        scB[cnt + lane] = make_float2(0.f, 0.f);
    }
    __syncthreads();   // single wave: compiles to waitcnt; orders LDS w->r
    const int n = (cnt + 3) & ~3;

    // thread -> pixel of this 8x8 tile
    const int lx = lane & (TS - 1);
    const int ly = lane >> 3;
    const int j  = jmin + lx;
    const int i  = imin + ly;
    const float px = (float)j;
    const float py = (float)(Hh - 1 - i);

    float ac0 = 0.f, ac1 = 0.f, ac2 = 0.f, ac3 = 0.f;

#define BODY(k, acc) {                                          \
        const float4 v = scA[e + (k)];                          \
        const float2 w = scB[e + (k)];                          \
        const float dx = px - v.x;                              \
        const float dy = py - v.y;                              \
        const float u_ = fmaf(dx, v.z, dy * v.w);               \
        const float t_ = fmaf(dy * dy, w.x, dx * u_);           \
        acc = fmaf(w.y, EXP2F(t_), acc);                        \
    }

    #pragma unroll 1
    for (int e = 0; e < n; e += 4) {
        BODY(0, ac0)
        BODY(1, ac1)
        BODY(2, ac2)
        BODY(3, ac3)
    }
#undef BODY

    if (i < Hh && j < Ww)
        out[b * NPIX + i * Ww + j] = (ac0 + ac1) + (ac2 + ac3);
}

extern "C" void kernel_launch(void* const* d_in, const int* in_sizes, int n_in,
                              void* d_out, int out_size, void* d_ws, size_t ws_size,
                              hipStream_t stream) {
    const float* stim   = (const float*)d_in[0];  // (8, 225, 3)
    const float* params = (const float*)d_in[1];  // (8, 13)
    const float* ex     = (const float*)d_in[2];  // (1, 225)
    const float* ey     = (const float*)d_in[3];  // (1, 225)
    const float* slopes = (const float*)d_in[4];  // (200, 200)
    // d_in[5] = pixelgrid: unused, indices derived analytically
    float* out = (float*)d_out;                   // (8, 121, 121) fp32

    // workspace layout: records re-written every call (ws is re-poisoned)
    float4* cullRec = (float4*)d_ws;                 // 8*256 * 16B
    float4* mARec   = cullRec + Bb * EPAD;           // 8*256 * 16B
    float2* mBRec   = (float2*)(mARec + Bb * EPAD);  // 8*256 *  8B

    mvg_precomp<<<dim3(Bb, 4), 64, 0, stream>>>(stim, params, ex, ey, slopes,
                                                cullRec, mARec, mBRec);
    mvg_render<<<dim3(16, 16, Bb), 64, 0, stream>>>(cullRec, mARec, mBRec, out);
}